// Round 6
// baseline (47445.035 us; speedup 1.0000x reference)
//
#include <hip/hip_runtime.h>
#include <hip/hip_bf16.h>
#include <cstdint>
#include <cstddef>

// Problem constants (reference: B,T,D,L = 64,256,1024,4; H = D)
#define B_ 64
#define T_ 256
#define D_ 1024
#define H_ 1024
#define G_ 4096   // 4*H
#define L_ 4

// ---------------------------------------------------------------------------
// GEMM for one time-chunk: O[r, :] = A_row(r) @ W + bias, r = b*Tc + tc,
// A_row(r) = A[b, t0+tc, :].  O is the compact xg chunk [B*Tc, 4H].
// BM=BN=128, BK=8, 256 threads, 8x8 micro-tile, register-prefetched loads.
// ---------------------------------------------------------------------------
__global__ __launch_bounds__(256) void gemm_bias_f32(
    const float* __restrict__ A,    // layer input [B, T, D]
    const float* __restrict__ W,    // [D, 4H]
    const float* __restrict__ bias, // [4H]
    float* __restrict__ O,          // xg chunk [B*Tc, 4H]
    int t0, int tshift)             // chunk start, log2(Tc)
{
  __shared__ float As[8][128];   // transposed A tile: As[k][m]
  __shared__ float Bs[8][128];   // Bs[k][n]
  const int tcmask = (1 << tshift) - 1;
  const int tid  = threadIdx.x;
  const int row0 = blockIdx.y * 128;
  const int col0 = blockIdx.x * 128;
  const int tr = tid >> 4;            // 0..15
  const int tc = tid & 15;            // 0..15
  const int ar = tid >> 1;            // 0..127  (A tile row)
  const int ac4 = (tid & 1) * 4;      // 0 or 4  (A tile col, float4)
  const int br = tid >> 5;            // 0..7    (B tile row)
  const int bc4 = (tid & 31) * 4;     // 0..124  (B tile col, float4)

  float acc[8][8];
#pragma unroll
  for (int i = 0; i < 8; ++i)
#pragma unroll
    for (int j = 0; j < 8; ++j) acc[i][j] = 0.f;

  const int ra  = row0 + ar;               // chunk row for the A load
  const int ab  = ra >> tshift;            // batch index
  const int att = t0 + (ra & tcmask);      // global timestep
  const float* Aptr = A + ((size_t)ab * T_ + att) * D_ + ac4;
  const float* Wptr = W + (size_t)br * G_ + col0 + bc4;

  float4 av = *(const float4*)(Aptr);
  float4 bv = *(const float4*)(Wptr);

  for (int kk = 0; kk < D_; kk += 8) {
    __syncthreads();                 // previous iter's LDS reads done
    As[ac4 + 0][ar] = av.x;
    As[ac4 + 1][ar] = av.y;
    As[ac4 + 2][ar] = av.z;
    As[ac4 + 3][ar] = av.w;
    *(float4*)&Bs[br][bc4] = bv;
    __syncthreads();
    if (kk + 8 < D_) {               // prefetch next tile; hides under compute
      av = *(const float4*)(Aptr + kk + 8);
      bv = *(const float4*)(Wptr + (size_t)(kk + 8) * G_);
    }
#pragma unroll
    for (int k = 0; k < 8; ++k) {
      float4 a0 = *(const float4*)&As[k][tr * 8];
      float4 a1 = *(const float4*)&As[k][tr * 8 + 4];
      float4 b0 = *(const float4*)&Bs[k][tc * 8];
      float4 b1 = *(const float4*)&Bs[k][tc * 8 + 4];
      float ra_[8] = {a0.x, a0.y, a0.z, a0.w, a1.x, a1.y, a1.z, a1.w};
      float rb_[8] = {b0.x, b0.y, b0.z, b0.w, b1.x, b1.y, b1.z, b1.w};
#pragma unroll
      for (int i = 0; i < 8; ++i)
#pragma unroll
        for (int j = 0; j < 8; ++j)
          acc[i][j] = fmaf(ra_[i], rb_[j], acc[i][j]);
    }
  }

#pragma unroll
  for (int i = 0; i < 8; ++i) {
    const int r = row0 + tr * 8 + i;        // chunk row
    float* op = O + (size_t)r * G_ + col0 + tc * 8;
    const float* bp = bias + col0 + tc * 8;
    float4 o0, o1;
    o0.x = acc[i][0] + bp[0]; o0.y = acc[i][1] + bp[1];
    o0.z = acc[i][2] + bp[2]; o0.w = acc[i][3] + bp[3];
    o1.x = acc[i][4] + bp[4]; o1.y = acc[i][5] + bp[5];
    o1.z = acc[i][6] + bp[6]; o1.w = acc[i][7] + bp[7];
    *(float4*)op = o0;
    *(float4*)(op + 4) = o1;
  }
}

// ---------------------------------------------------------------------------
// Persistent LSTM scan for one time-chunk of one layer.
// grid = 256 WGs (1 per CU): 2 batch-chunks (32 rows) x 128 j-tiles (8 j each).
// Wh slice [1024 x 32 gate-cols] lives in LDS (128 KiB) for the whole chunk.
// Thread tid = rb*64 + q*8 + ks: rb = row-block (8 rows), q = j within tile,
// ks = K-slice (128 wide). Partials reduced over ks via shfl_xor butterfly
// (row ownership after 3 stages = ks, verified by trace).
// h history IS the y output buffer (d_out): step t reads y[:, t-1, :].
// c state persists across chunk launches in cbuf. Inter-WG sync per step:
// monotonic per-group atomic counter + device-scope fences (h crosses XCDs).
// LDS bank audit: Whs4[k*8+q] reads put exactly 8 distinct words on every
// bank per phase == the 64-lane b128 floor; balanced, no swizzle needed.
// ---------------------------------------------------------------------------
__global__ __launch_bounds__(256, 1) void lstm_scan_f32(
    const float* __restrict__ xg,  // [B*Tc, 4H] this chunk's input gates
    const float* __restrict__ Wh,  // [H, 4H] this layer
    float* __restrict__ y,         // [B, T, H] output (= h history, in-place)
    float* __restrict__ cbuf,      // [B, H] cell state across chunks
    int* __restrict__ bar,         // 2 counters, 256B apart
    int t0, int tshift)            // chunk start, log2(Tc)
{
  extern __shared__ float Whs[];   // [1024][32], col = q*4 + gate
  const int Tc  = 1 << tshift;
  const int wg  = blockIdx.x;
  const int bc  = wg >> 7;         // 0..1 batch-chunk
  const int nt  = wg & 127;        // 0..127 j-tile
  const int j0  = nt * 8;
  const int tid = threadIdx.x;
  const int rb  = tid >> 6;        // 0..3
  const int q   = (tid >> 3) & 7;  // 0..7
  const int ks  = tid & 7;         // 0..7

  // ---- stage Wh slice -> LDS (once per launch) ----
  for (int e = tid; e < 8192; e += 256) {       // 8192 float4 = 128 KiB
    const int k = e >> 3, rem = e & 7, g = rem >> 1, half = rem & 1;
    float4 v = *(const float4*)&Wh[(size_t)k * G_ + g * H_ + j0 + half * 4];
    const int qb = half * 4;
    Whs[k * 32 + (qb + 0) * 4 + g] = v.x;
    Whs[k * 32 + (qb + 1) * 4 + g] = v.y;
    Whs[k * 32 + (qb + 2) * 4 + g] = v.z;
    Whs[k * 32 + (qb + 3) * 4 + g] = v.w;
  }
  __syncthreads();

  const int row_out = bc * 32 + rb * 8 + ks;    // this thread's output row
  size_t rowoff[8];
#pragma unroll
  for (int u = 0; u < 8; ++u)
    rowoff[u] = (size_t)(bc * 32 + rb * 8 + u) * T_ * H_;

  int* cnt = bar + bc * 64;                     // separate cacheline per group
  float c_state = (t0 > 0) ? cbuf[(size_t)row_out * H_ + j0 + q] : 0.f;
  const float4* Whs4 = (const float4*)Whs;

  for (int s = 0; s < Tc; ++s) {
    const int t = t0 + s;
    float pa[8][4];
#pragma unroll
    for (int u = 0; u < 8; ++u)
#pragma unroll
      for (int g = 0; g < 4; ++g) pa[u][g] = 0.f;

    if (t > 0) {
      if (s > 0) {
        // ---- group barrier: all 128 WGs of this group wrote step t-1 ----
        __syncthreads();
        if (tid == 0) {
          __threadfence();                      // release h writes (LLC)
          __hip_atomic_fetch_add(cnt, 1, __ATOMIC_RELAXED,
                                 __HIP_MEMORY_SCOPE_AGENT);
          const int target = 128 * s;
          while (__hip_atomic_load(cnt, __ATOMIC_RELAXED,
                                   __HIP_MEMORY_SCOPE_AGENT) < target)
            __builtin_amdgcn_s_sleep(8);
          __threadfence();                      // acquire
        }
        __syncthreads();
      }
      // (s == 0, t0 > 0: previous chunk's launch boundary is the sync)

      const float* hbase = y + (size_t)(t - 1) * H_;
      const float4* hp[8];
#pragma unroll
      for (int u = 0; u < 8; ++u)
        hp[u] = (const float4*)(hbase + rowoff[u]) + ks * 32;

#pragma unroll 2
      for (int kk4 = 0; kk4 < 32; ++kk4) {
        const int k = ks * 128 + kk4 * 4;
        float4 w0 = Whs4[(k + 0) * 8 + q];
        float4 w1 = Whs4[(k + 1) * 8 + q];
        float4 w2 = Whs4[(k + 2) * 8 + q];
        float4 w3 = Whs4[(k + 3) * 8 + q];
        float4 hv[8];
#pragma unroll
        for (int u = 0; u < 8; ++u) hv[u] = hp[u][kk4];
#pragma unroll
        for (int u = 0; u < 8; ++u) {
          const float h0 = hv[u].x, h1 = hv[u].y, h2 = hv[u].z, h3 = hv[u].w;
          pa[u][0] = fmaf(h0, w0.x, pa[u][0]);
          pa[u][1] = fmaf(h0, w0.y, pa[u][1]);
          pa[u][2] = fmaf(h0, w0.z, pa[u][2]);
          pa[u][3] = fmaf(h0, w0.w, pa[u][3]);
          pa[u][0] = fmaf(h1, w1.x, pa[u][0]);
          pa[u][1] = fmaf(h1, w1.y, pa[u][1]);
          pa[u][2] = fmaf(h1, w1.z, pa[u][2]);
          pa[u][3] = fmaf(h1, w1.w, pa[u][3]);
          pa[u][0] = fmaf(h2, w2.x, pa[u][0]);
          pa[u][1] = fmaf(h2, w2.y, pa[u][1]);
          pa[u][2] = fmaf(h2, w2.z, pa[u][2]);
          pa[u][3] = fmaf(h2, w2.w, pa[u][3]);
          pa[u][0] = fmaf(h3, w3.x, pa[u][0]);
          pa[u][1] = fmaf(h3, w3.y, pa[u][1]);
          pa[u][2] = fmaf(h3, w3.z, pa[u][2]);
          pa[u][3] = fmaf(h3, w3.w, pa[u][3]);
        }
      }
    }

    // ---- reduce partials over the 8 ks lanes (butterfly, row-specializing) --
    const bool hi4 = (ks & 4) != 0;
    float s1[4][4];
#pragma unroll
    for (int i = 0; i < 4; ++i)
#pragma unroll
      for (int g = 0; g < 4; ++g) {
        float send = hi4 ? pa[i][g] : pa[i + 4][g];
        float keep = hi4 ? pa[i + 4][g] : pa[i][g];
        s1[i][g] = keep + __shfl_xor(send, 4);
      }
    const bool hi2 = (ks & 2) != 0;
    float s2[2][4];
#pragma unroll
    for (int i = 0; i < 2; ++i)
#pragma unroll
      for (int g = 0; g < 4; ++g) {
        float send = hi2 ? s1[i][g] : s1[i + 2][g];
        float keep = hi2 ? s1[i + 2][g] : s1[i][g];
        s2[i][g] = keep + __shfl_xor(send, 2);
      }
    const bool hi1 = (ks & 1) != 0;
    float gate[4];
#pragma unroll
    for (int g = 0; g < 4; ++g) {
      float send = hi1 ? s2[0][g] : s2[1][g];
      float keep = hi1 ? s2[1][g] : s2[0][g];
      gate[g] = keep + __shfl_xor(send, 1);
    }

    // ---- gates + state update + write h ----
    const float* xgp = xg + (((size_t)row_out << tshift) + s) * G_ + j0 + q;
    const float gi = gate[0] + xgp[0];
    const float gf = gate[1] + xgp[H_];
    const float gg = gate[2] + xgp[2 * H_];
    const float go = gate[3] + xgp[3 * H_];
    const float iv = 1.f / (1.f + expf(-gi));
    const float fv = 1.f / (1.f + expf(-gf));
    const float gv = tanhf(gg);
    const float ov = 1.f / (1.f + expf(-go));
    c_state = fv * c_state + iv * gv;
    const float hout = ov * tanhf(c_state);
    y[((size_t)row_out * T_ + t) * H_ + j0 + q] = hout;
  }

  cbuf[(size_t)row_out * H_ + j0 + q] = c_state;   // persist across chunks
}

// ---------------------------------------------------------------------------
extern "C" void kernel_launch(void* const* d_in, const int* in_sizes, int n_in,
                              void* d_out, int out_size, void* d_ws, size_t ws_size,
                              hipStream_t stream)
{
  const float* x  = (const float*)d_in[0];   // [B,T,D]
  const float* Wi = (const float*)d_in[1];   // [L,D,4H]
  const float* Wh = (const float*)d_in[2];   // [L,H,4H]
  const float* b  = (const float*)d_in[3];   // [L,4H]
  float* out = (float*)d_out;                // [B,T,H] — also every layer's y

  // Workspace layout (adaptive to ws_size):
  //   [0,1KiB)        barrier counters
  //   [1KiB,257KiB)   c-state [B,H] f32
  //   [257KiB, ...)   xg chunk [B*Tc, 4H] f32  (Tc chosen to fit; >=2)
  char* ws = (char*)d_ws;
  int*   bar  = (int*)ws;
  float* cbuf = (float*)(ws + 1024);
  float* xg   = (float*)(ws + 1024 + 262144);
  const size_t fixed = 1024 + 262144;
  int Tc = 256;
  while (Tc > 2 && fixed + (size_t)B_ * Tc * G_ * 4 > ws_size) Tc >>= 1;
  int tshift = 0; while ((1 << tshift) < Tc) ++tshift;
  const int nc = T_ / Tc;

  // allow 128 KiB dynamic LDS (idempotent, graph-safe host-side call)
  hipFuncSetAttribute((const void*)lstm_scan_f32,
                      hipFuncAttributeMaxDynamicSharedMemorySize, 131072);

  const float* in = x;                       // layer 0 reads x; others read out
  for (int l = 0; l < L_; ++l) {
    const float* Wl = Wi + (size_t)l * D_ * G_;
    const float* bl = b  + (size_t)l * G_;
    const float* Wr = Wh + (size_t)l * H_ * G_;
    for (int c = 0; c < nc; ++c) {
      const int t0 = c * Tc;
      dim3 ggrid(G_ / 128, (B_ * Tc) / 128);
      gemm_bias_f32<<<ggrid, 256, 0, stream>>>(in, Wl, bl, xg, t0, tshift);
      hipMemsetAsync(bar, 0, 1024, stream);  // zero barrier counters
      lstm_scan_f32<<<256, 256, 131072, stream>>>(xg, Wr, out, cbuf, bar,
                                                  t0, tshift);
    }
    in = out;                                // layers are in-place in d_out
  }
}